// Round 13
// baseline (315.974 us; speedup 1.0000x reference)
//
#include <hip/hip_runtime.h>
#include <math.h>

#define S 1024
#define DM 512
#define H 8
#define HD 64
#define NH 8          // n_hashes
#define NB 16         // n_buckets
#define N 8192        // B*H*S
#define SCALE 0.125f  // 1/sqrt(64)
#define EXP2C 0.18033688f  // SCALE * log2(e)

typedef __attribute__((ext_vector_type(4))) float f32x4;
typedef __attribute__((ext_vector_type(8))) short s16x8;
typedef __attribute__((ext_vector_type(4))) short s16x4;

__device__ __forceinline__ short f2bf(float f) {  // RTNE float->bf16
  union { float f; unsigned u; } a; a.f = f;
  unsigned r = a.u + 0x7fffu + ((a.u >> 16) & 1u);
  return (short)(r >> 16);
}
__device__ __forceinline__ float bf2f(short h) {
  union { unsigned u; float f; } a; a.u = ((unsigned)(unsigned short)h) << 16;
  return a.f;
}
__device__ __forceinline__ int f2bf2(float lo, float hi) {
  return (int)(unsigned short)f2bf(lo) | (((int)f2bf(hi)) << 16);
}
// level-l component of the 3-way bf16 split x = x0 + x1 + x2 (+eps)
__device__ __forceinline__ short lev_bf(float v, int lev) {
  short h0 = f2bf(v);
  if (lev == 0) return h0;
  float r1 = v - bf2f(h0);
  short h1 = f2bf(r1);
  if (lev == 1) return h1;
  return f2bf(r1 - bf2f(h1));
}

#if __has_builtin(__builtin_amdgcn_mfma_f32_16x16x16_bf16)
#define MFMA_PV(a, b, c) __builtin_amdgcn_mfma_f32_16x16x16_bf16(a, b, c, 0, 0, 0)
#else
#define MFMA_PV(a, b, c) __builtin_amdgcn_mfma_f32_16x16x16bf16_1k(a, b, c, 0, 0, 0)
#endif

// ---------------- K0: weight prep — Wt[lev][d][k] bf16 (transposed, split)
__global__ __launch_bounds__(256) void wprep_kernel(
    const float* __restrict__ wqk, const float* __restrict__ wv,
    const float* __restrict__ wo,
    short* __restrict__ wtqk, short* __restrict__ wtv, short* __restrict__ wto,
    int* __restrict__ cz) {
  int tid = threadIdx.x;
  if (blockIdx.x == 0) cz[tid] = 0;   // cursor[128] + pad
  int mat = blockIdx.x >> 6;          // 0 qk, 1 v, 2 o
  int tile = blockIdx.x & 63;
  int kt = tile >> 3, dt = tile & 7;
  const float* w = (mat == 0) ? wqk : ((mat == 1) ? wv : wo);

  __shared__ float wlds[64 * 68];
  int kr = tid >> 2, c4 = tid & 3;
  const float4* src = (const float4*)(w + (size_t)(kt * 64 + kr) * DM + dt * 64 + c4 * 16);
#pragma unroll
  for (int i = 0; i < 4; ++i) {
    float4 v = src[i];
    float* d = &wlds[kr * 68 + c4 * 16 + i * 4];
    d[0] = v.x; d[1] = v.y; d[2] = v.z; d[3] = v.w;
  }
  __syncthreads();
  int dr = tid >> 2, kc = tid & 3;
  s16x8 h0a, h0b, h1a, h1b, h2a, h2b;
#pragma unroll
  for (int i = 0; i < 8; ++i) {
    float v = wlds[(kc * 16 + i) * 68 + dr];
    short a = f2bf(v); float r1 = v - bf2f(a);
    short b = f2bf(r1); short c = f2bf(r1 - bf2f(b));
    h0a[i] = a; h1a[i] = b; h2a[i] = c;
  }
#pragma unroll
  for (int i = 0; i < 8; ++i) {
    float v = wlds[(kc * 16 + 8 + i) * 68 + dr];
    short a = f2bf(v); float r1 = v - bf2f(a);
    short b = f2bf(r1); short c = f2bf(r1 - bf2f(b));
    h0b[i] = a; h1b[i] = b; h2b[i] = c;
  }
  size_t dst = (size_t)(dt * 64 + dr) * DM + kt * 64 + kc * 16;
  if (mat == 0) {
    s16x8* p0 = (s16x8*)(wtqk + dst);
    s16x8* p1 = (s16x8*)(wtqk + (size_t)DM * DM + dst);
    s16x8* p2 = (s16x8*)(wtqk + (size_t)2 * DM * DM + dst);
    p0[0] = h0a; p0[1] = h0b; p1[0] = h1a; p1[1] = h1b; p2[0] = h2a; p2[1] = h2b;
  } else if (mat == 1) {
    s16x8* p = (s16x8*)(wtv + dst); p[0] = h0a; p[1] = h0b;
  } else {
    s16x8* p = (s16x8*)(wto + dst); p[0] = h0a; p[1] = h0b;
  }
}

// ---------------- K1: MFMA projection GEMM, split-K balanced (verbatim)
#define PST 72
__global__ __launch_bounds__(256) void projmm_kernel(
    const float* __restrict__ x, const short* __restrict__ wtqk,
    const short* __restrict__ wtv,
    const float* __restrict__ bqk, const float* __restrict__ bv,
    float* __restrict__ qkpart, short* __restrict__ vb) {
  int mt = blockIdx.x & 15;
  int rest = blockIdx.x >> 4;   // 0..55
  int sp = rest >> 3;           // 0..5 qk split, 6 = v
  int head = rest & 7;
  bool isv = (sp == 6);
  int xl = isv ? 0 : ((0x210100 >> (sp << 2)) & 0xF);  // {0,0,1,0,1,2}
  int wl = isv ? 0 : ((0x012010 >> (sp << 2)) & 0xF);  // {0,1,0,2,1,0}
  const short* wt = isv ? wtv : (wtqk + (size_t)wl * DM * DM);

  __shared__ short a_lds[2][64 * PST];
  __shared__ short b_lds[2][64 * PST];

  int tid = threadIdx.x;
  int wave = tid >> 6, lane = tid & 63;
  int col = lane & 15, quad = lane >> 4;
  int mh = wave & 1, nh2 = wave >> 1;

  f32x4 acc[2][2];
#pragma unroll
  for (int i = 0; i < 2; ++i)
#pragma unroll
    for (int j = 0; j < 2; ++j) acc[i][j] = (f32x4){0.f, 0.f, 0.f, 0.f};

  int sr = tid >> 2, c4 = tid & 3;
  int gran = sr * PST + ((c4 ^ (sr & 3)) << 4);

  {  // stage chunk 0 into buffer 0
    const float4* xp = (const float4*)(x + (size_t)(mt * 64 + sr) * DM + c4 * 16);
    float4 f0 = xp[0], f1 = xp[1], f2 = xp[2], f3 = xp[3];
    float vv[16] = {f0.x,f0.y,f0.z,f0.w, f1.x,f1.y,f1.z,f1.w,
                    f2.x,f2.y,f2.z,f2.w, f3.x,f3.y,f3.z,f3.w};
    s16x8 ha, hb;
#pragma unroll
    for (int i = 0; i < 8; ++i) { ha[i] = lev_bf(vv[i], xl); hb[i] = lev_bf(vv[8 + i], xl); }
    s16x8* ad = (s16x8*)&a_lds[0][gran];
    ad[0] = ha; ad[1] = hb;
    const s16x8* wp = (const s16x8*)(wt + (size_t)(head * 64 + sr) * DM + c4 * 16);
    s16x8* bd = (s16x8*)&b_lds[0][gran];
    bd[0] = wp[0]; bd[1] = wp[1];
  }
  __syncthreads();

  for (int ci = 0; ci < 8; ++ci) {
    int cur = ci & 1, nxt = cur ^ 1;
    float4 pf0, pf1, pf2, pf3; s16x8 pw0, pw1;
    bool has = (ci + 1) < 8;
    if (has) {
      int kc = ci + 1;
      const float4* xp = (const float4*)(x + (size_t)(mt * 64 + sr) * DM + kc * 64 + c4 * 16);
      pf0 = xp[0]; pf1 = xp[1]; pf2 = xp[2]; pf3 = xp[3];
      const s16x8* wp = (const s16x8*)(wt + (size_t)(head * 64 + sr) * DM + kc * 64 + c4 * 16);
      pw0 = wp[0]; pw1 = wp[1];
    }
#pragma unroll
    for (int s2 = 0; s2 < 2; ++s2) {
      s16x8 af[2], bfv[2];
#pragma unroll
      for (int mi = 0; mi < 2; ++mi) {
        int row = mh * 32 + mi * 16 + col;
        int cidx = ((s2 << 1) + (quad >> 1)) ^ (row & 3);
        af[mi] = *(const s16x8*)&a_lds[cur][row * PST + (cidx << 4) + ((quad & 1) << 3)];
      }
#pragma unroll
      for (int ni = 0; ni < 2; ++ni) {
        int row = nh2 * 32 + ni * 16 + col;
        int cidx = ((s2 << 1) + (quad >> 1)) ^ (row & 3);
        bfv[ni] = *(const s16x8*)&b_lds[cur][row * PST + (cidx << 4) + ((quad & 1) << 3)];
      }
#pragma unroll
      for (int mi = 0; mi < 2; ++mi)
#pragma unroll
        for (int ni = 0; ni < 2; ++ni)
          acc[mi][ni] = __builtin_amdgcn_mfma_f32_16x16x32_bf16(af[mi], bfv[ni],
                                                               acc[mi][ni], 0, 0, 0);
    }
    if (has) {
      float vv[16] = {pf0.x,pf0.y,pf0.z,pf0.w, pf1.x,pf1.y,pf1.z,pf1.w,
                      pf2.x,pf2.y,pf2.z,pf2.w, pf3.x,pf3.y,pf3.z,pf3.w};
      s16x8 ha, hb;
#pragma unroll
      for (int i = 0; i < 8; ++i) { ha[i] = lev_bf(vv[i], xl); hb[i] = lev_bf(vv[8 + i], xl); }
      s16x8* ad = (s16x8*)&a_lds[nxt][gran];
      ad[0] = ha; ad[1] = hb;
      s16x8* bd = (s16x8*)&b_lds[nxt][gran];
      bd[0] = pw0; bd[1] = pw1;
    }
    __syncthreads();
  }
  if (isv) {
#pragma unroll
    for (int ni = 0; ni < 2; ++ni) {
      int nl = nh2 * 32 + ni * 16 + col;
      float bb = bv[head * 64 + nl];
#pragma unroll
      for (int mi = 0; mi < 2; ++mi)
#pragma unroll
        for (int u = 0; u < 4; ++u) {
          int s = mt * 64 + mh * 32 + mi * 16 + quad * 4 + u;
          vb[((size_t)head * S + s) * HD + nl] = f2bf(acc[mi][ni][u] + bb);
        }
    }
  } else {
    float* dst = qkpart + (size_t)sp * N * HD;
#pragma unroll
    for (int ni = 0; ni < 2; ++ni) {
      int nl = nh2 * 32 + ni * 16 + col;
      float bb = (sp == 0) ? bqk[head * 64 + nl] : 0.f;
#pragma unroll
      for (int mi = 0; mi < 2; ++mi)
#pragma unroll
        for (int u = 0; u < 4; ++u) {
          int s = mt * 64 + mh * 32 + mi * 16 + quad * 4 + u;
          dst[((size_t)head * S + s) * HD + nl] = acc[mi][ni][u] + bb;
        }
    }
  }
}

// ---------------- K2a: collapse the 6 fp32 slabs once -> qkf fp32 + qkb bf16
__global__ __launch_bounds__(256) void sumslab_kernel(
    const float* __restrict__ qkpart, float* __restrict__ qkf,
    short* __restrict__ qkb) {
  int idx = blockIdx.x * 256 + threadIdx.x;  // 0 .. N*HD/4 - 1
  f32x4 s = ((const f32x4*)qkpart)[idx];
#pragma unroll
  for (int sl = 1; sl < 6; ++sl)
    s += ((const f32x4*)(qkpart + (size_t)sl * N * HD))[idx];
  ((f32x4*)qkf)[idx] = s;
  int2 pk = make_int2(f2bf2(s[0], s[1]), f2bf2(s[2], s[3]));
  *(int2*)(qkb + (size_t)idx * 4) = pk;
}

// ---------------- K2b: LSH buckets + DIRECT per-bucket list build (scatter
// fused; order within a bucket is irrelevant to the masked softmax). q
// preloaded to registers for load overlap; rotation block staged in LDS.
__global__ __launch_bounds__(256) void bucket_kernel(
    const float* __restrict__ qkf, const float* __restrict__ rot,
    int* __restrict__ cursor, int* __restrict__ perm2) {
  __shared__ float Rl[HD * 8];   // 2 KB
  int tid = threadIdx.x;
  int g = blockIdx.x * 256 + tid;
  int n = g & (N - 1);
  int r = g >> 13;
  int h = n >> 10;
  int lane = tid & 63;
  const float* R = rot + (size_t)((r * H + h) * HD) * 8;
  if (tid < 128) ((f32x4*)Rl)[tid] = ((const f32x4*)R)[tid];

  f32x4 qv[16];
  const f32x4* q4 = (const f32x4*)(qkf + (size_t)n * HD);
#pragma unroll
  for (int d4 = 0; d4 < 16; ++d4) qv[d4] = q4[d4];
  __syncthreads();

  float v[8];
#pragma unroll
  for (int c = 0; c < 8; ++c) v[c] = 0.f;
#pragma unroll
  for (int d4 = 0; d4 < 16; ++d4) {
    f32x4 q = qv[d4];
#pragma unroll
    for (int j = 0; j < 4; ++j) {
      const f32x4* Rr = (const f32x4*)&Rl[(d4 * 4 + j) * 8];
      f32x4 r0 = Rr[0], r1 = Rr[1];
      float qj = q[j];
#pragma unroll
      for (int c = 0; c < 4; ++c) v[c] = fmaf(qj, r0[c], v[c]);
#pragma unroll
      for (int c = 0; c < 4; ++c) v[4 + c] = fmaf(qj, r1[c], v[4 + c]);
    }
  }
  float best = v[0];
  int bi = 0;
#pragma unroll
  for (int c = 1; c < 16; ++c) {
    float val = (c < 8) ? v[c] : -v[c - 8];
    if (val > best) { best = val; bi = c; }
  }
  for (int bk = 0; bk < NB; ++bk) {
    unsigned long long mask = __ballot(bi == bk);
    if (!mask) continue;
    int leader = __ffsll((long long)mask) - 1;
    int base = 0;
    if (lane == leader) base = atomicAdd(&cursor[(r << 4) + bk], __popcll(mask));
    base = __shfl(base, leader);
    if (bi == bk) {
      int rank = __popcll(mask & ((1ull << lane) - 1ull));
      perm2[(((size_t)(r << 4) + bk) << 13) + base + rank] = n;
    }
  }
}

// ---------------- K3: MFMA attention over per-bucket lists. Grid =
// (r, bucket, 128-query chunk); all queries of a block share one bucket, so
// masking exists only at the tail. V in natural [key][dim] rows (r11 layout,
// ~1.1M conflicts vs 3.95M transposed). bf16 normalized output.
#define KT 64
#define KST 72
#define VST 72
__global__ __launch_bounds__(512) void attn_kernel(
    const short* __restrict__ qkb, const short* __restrict__ vb,
    const int* __restrict__ perm2, const int* __restrict__ cursor,
    short* __restrict__ accumB) {
  int bx = blockIdx.x;
  int r = bx >> 10;
  int b = (bx >> 6) & 15;
  int chunk = bx & 63;
  int cnt = cursor[(r << 4) + b];
  int q0 = chunk << 7;
  if (q0 >= cnt) return;
  const int* plist = perm2 + (((size_t)(r << 4) + b) << 13);

  int tid = threadIdx.x;
  int wave = tid >> 6, lane = tid & 63;
  int col = lane & 15, quad = lane >> 4;

  __shared__ short k_lds[2][KT * KST];
  __shared__ short v_lds[2][KT * VST];

  int qslot = q0 + (wave << 4) + col;
  bool qvalid = qslot < cnt;
  int qidx = plist[qvalid ? qslot : 0];

  for (int e = tid; e < KT * VST; e += 512) ((int*)v_lds)[e] = 0;

  s16x8 qa[2];
#pragma unroll
  for (int s2 = 0; s2 < 2; ++s2)
    qa[s2] = *(const s16x8*)(qkb + (size_t)qidx * HD + s2 * 32 + quad * 8);
  __syncthreads();   // zero-init fully retired before staging writes

  float lsum = 0.f;
  f32x4 o0 = {0,0,0,0}, o1 = {0,0,0,0}, o2 = {0,0,0,0}, o3 = {0,0,0,0};

  int jsk = tid >> 2, csk = tid & 3;
  bool stager = tid < 256;
  int kgran = jsk * KST + ((csk ^ (jsk & 3)) << 4);
  int vgran = jsk * VST + (csk << 4);

  {  // stage tile 0 into buffer 0
    int nj = min(KT, cnt);
    if (stager && jsk < nj) {
      int gk = plist[jsk];
      const s16x8* kp = (const s16x8*)(qkb + (size_t)gk * HD + (csk << 4));
      const s16x8* vp = (const s16x8*)(vb + (size_t)gk * HD + (csk << 4));
      s16x8 a0 = kp[0], a1 = kp[1], b0 = vp[0], b1 = vp[1];
      s16x8* kd = (s16x8*)&k_lds[0][kgran];
      kd[0] = a0; kd[1] = a1;
      s16x8* vd = (s16x8*)&v_lds[0][vgran];
      vd[0] = b0; vd[1] = b1;
    }
  }
  __syncthreads();

  int ntiles = (cnt + KT - 1) >> 6;
  for (int t = 0; t < ntiles; ++t) {
    int jt = t << 6;
    int cur = t & 1, nxt = cur ^ 1;
    s16x8 a0, a1, b0, b1;
    bool pf_ok = false;
    int jn = jt + KT;
    if (jn < cnt && stager) {
      int njn = min(KT, cnt - jn);
      if (jsk < njn) {
        pf_ok = true;
        int gk = plist[jn + jsk];
        const s16x8* kp = (const s16x8*)(qkb + (size_t)gk * HD + (csk << 4));
        const s16x8* vp = (const s16x8*)(vb + (size_t)gk * HD + (csk << 4));
        a0 = kp[0]; a1 = kp[1]; b0 = vp[0]; b1 = vp[1];
      }
    }
    int c_hi = min(4, (cnt - jt + 15) >> 4);
    for (int c16 = 0; c16 < c_hi; ++c16) {
      f32x4 sacc = {0,0,0,0};
      int key = (c16 << 4) + col;
      const short* kb = &k_lds[cur][key * KST];
#pragma unroll
      for (int s2 = 0; s2 < 2; ++s2) {
        int cidx = ((s2 << 1) + (quad >> 1)) ^ (key & 3);
        s16x8 kf = *(const s16x8*)&kb[(cidx << 4) + ((quad & 1) << 3)];
        sacc = __builtin_amdgcn_mfma_f32_16x16x32_bf16(kf, qa[s2], sacc, 0, 0, 0);
      }
      int kbase = jt + (c16 << 4) + (quad << 2);
      float pw[4];
      if (kbase + 4 <= cnt) {           // full chunk: no masking
#pragma unroll
        for (int u = 0; u < 4; ++u) pw[u] = exp2f(sacc[u] * EXP2C);
      } else {
#pragma unroll
        for (int u = 0; u < 4; ++u)
          pw[u] = (kbase + u < cnt) ? exp2f(sacc[u] * EXP2C) : 0.f;
      }
      lsum += (pw[0] + pw[1]) + (pw[2] + pw[3]);
      s16x4 pfr;
      pfr[0] = f2bf(pw[0]); pfr[1] = f2bf(pw[1]);
      pfr[2] = f2bf(pw[2]); pfr[3] = f2bf(pw[3]);
      const short* vbp = &v_lds[cur][((c16 << 4) + (quad << 2)) * VST + col];
#pragma unroll
      for (int c = 0; c < 4; ++c) {
        s16x4 vfr;
#pragma unroll
        for (int j = 0; j < 4; ++j)
          vfr[j] = vbp[j * VST + (c << 4)];
        if (c == 0) o0 = MFMA_PV(pfr, vfr, o0);
        else if (c == 1) o1 = MFMA_PV(pfr, vfr, o1);
        else if (c == 2) o2 = MFMA_PV(pfr, vfr, o2);
        else o3 = MFMA_PV(pfr, vfr, o3);
      }
    }
    if (pf_ok) {
      s16x8* kd = (s16x8*)&k_lds[nxt][kgran];
      kd[0] = a0; kd[1] = a1;
      s16x8* vd = (s16x8*)&v_lds[nxt][vgran];
      vd[0] = b0; vd[1] = b1;
    }
    __syncthreads();
  }

  lsum += __shfl_xor(lsum, 16);
  lsum += __shfl_xor(lsum, 32);
  float inv = 1.f / lsum;
#pragma unroll
  for (int u = 0; u < 4; ++u) {
    int slot = (quad << 2) + u;
    int spos = q0 + (wave << 4) + slot;
    float inv_u = __shfl(inv, slot);
    int qidx_u = __shfl(qidx, slot);
    if (spos < cnt) {
      short* dst = accumB + ((size_t)r * N + qidx_u) * HD + col;
      dst[0]  = f2bf(o0[u] * inv_u);
      dst[16] = f2bf(o1[u] * inv_u);
      dst[32] = f2bf(o2[u] * inv_u);
      dst[48] = f2bf(o3[u] * inv_u);
    }
  }
}

// ---------------- K4: MFMA output projection; A from bf16 accumB (verbatim)
__global__ __launch_bounds__(256) void outproj_kernel(
    const short* __restrict__ accumB, const short* __restrict__ wto,
    const float* __restrict__ bo, float* __restrict__ out) {
  int mt = blockIdx.x & 31;   // s-tile of 32
  int nt = blockIdx.x >> 5;   // d-tile of 64
  __shared__ short a_lds[2][32 * PST];
  __shared__ short b_lds[2][64 * PST];
  int tid = threadIdx.x;
  int wave = tid >> 6, lane = tid & 63;
  int col = lane & 15, quad = lane >> 4;
  int mi2 = wave & 1, nh2 = wave >> 1;

  f32x4 acc[2];
  acc[0] = (f32x4){0.f,0.f,0.f,0.f};
  acc[1] = (f32x4){0.f,0.f,0.f,0.f};

  bool isA = tid < 128;
  int sr = tid >> 2, c4 = tid & 3;
  int agran = sr * PST + ((c4 ^ (sr & 3)) << 4);
  int dl = (tid - 128) >> 1, gp = tid & 1;

  {  // stage chunk 0
    if (isA) {
      size_t abase = ((size_t)0 * S + mt * 32 + sr) * HD + c4 * 16;
      float a16[16];
#pragma unroll
      for (int i = 0; i < 16; ++i) a16[i] = 0.f;
#pragma unroll
      for (int r = 0; r < NH; ++r) {
        const short* ap = accumB + (size_t)r * N * HD + abase;
        s16x8 h0 = *(const s16x8*)ap, h1 = *(const s16x8*)(ap + 8);
#pragma unroll
        for (int i = 0; i < 8; ++i) { a16[i] += bf2f(h0[i]); a16[8 + i] += bf2f(h1[i]); }
      }
      s16x8 ha, hb;
#pragma unroll
      for (int i = 0; i < 8; ++i) {
        ha[i] = f2bf(a16[i] * 0.125f); hb[i] = f2bf(a16[8 + i] * 0.125f);
      }
      s16x8* ad = (s16x8*)&a_lds[0][agran];
      ad[0] = ha; ad[1] = hb;
    } else {
      const s16x8* wp = (const s16x8*)(wto + (size_t)(nt * 64 + dl) * DM + gp * 32);
      int g0 = gp * 2;
      s16x8* d0 = (s16x8*)&b_lds[0][dl * PST + ((g0 ^ (dl & 3)) << 4)];
      d0[0] = wp[0]; d0[1] = wp[1];
      s16x8* d1 = (s16x8*)&b_lds[0][dl * PST + (((g0 + 1) ^ (dl & 3)) << 4)];
      d1[0] = wp[2]; d1[1] = wp[3];
    }
  }
  __syncthreads();

  for (int kc = 0; kc < 8; ++kc) {
    int cur = kc & 1, nxt = cur ^ 1;
    bool has = kc + 1 < 8;
    float a16[16];
    s16x8 pb0, pb1, pb2, pb3;
    if (has) {
      if (isA) {
        size_t abase = ((size_t)(kc + 1) * S + mt * 32 + sr) * HD + c4 * 16;
#pragma unroll
        for (int i = 0; i < 16; ++i) a16[i] = 0.f;
#pragma unroll
        for (int r = 0; r < NH; ++r) {
          const short* ap = accumB + (size_t)r * N * HD + abase;
          s16x8 h0 = *(const s16x8*)ap, h1 = *(const s16x8*)(ap + 8);
#pragma unroll
          for (int i = 0; i < 8; ++i) { a16[i] += bf2f(h0[i]); a16[8 + i] += bf2f(h1[i]); }
        }
      } else {
        const s16x8* wp = (const s16x8*)(wto + (size_t)(nt * 64 + dl) * DM +
                                         (kc + 1) * 64 + gp * 32);
        pb0 = wp[0]; pb1 = wp[1]; pb2 = wp[2]; pb3 = wp[3];
      }
    }
#pragma unroll
    for (int s2 = 0; s2 < 2; ++s2) {
      int arow = mi2 * 16 + col;
      int acidx = ((s2 << 1) + (quad >> 1)) ^ (arow & 3);
      s16x8 af = *(const s16x8*)&a_lds[cur][arow * PST + (acidx << 4) + ((quad & 1) << 3)];
      s16x8 bfv[2];
#pragma unroll
      for (int ni = 0; ni < 2; ++ni) {
        int brow = nh2 * 32 + ni * 16 + col;
        int bcidx = ((s2 << 1) + (quad >> 1)) ^ (brow & 3);
        bfv[ni] = *(const s16x8*)&b_lds[cur][brow * PST + (bcidx << 4) + ((quad & 1) << 3)];
      }
#pragma unroll
      for (int ni = 0; ni < 2; ++ni)
        acc[ni] = __builtin_amdgcn_mfma_f32_16x16x32_bf16(af, bfv[ni], acc[ni], 0, 0, 0);
    }
    if (has) {
      if (isA) {
        s16x8 ha, hb;
#pragma unroll
        for (int i = 0; i < 8; ++i) {
          ha[i] = f2bf(a16[i] * 0.125f); hb[i] = f2bf(a16[8 + i] * 0.125f);
        }
        s16x8* ad = (s16x8*)&a_lds[nxt][agran];
        ad[0] = ha; ad[1] = hb;
      } else {
        int g0 = gp * 2;
        s16x8* d0 = (s16x8*)&b_lds[nxt][dl * PST + ((g0 ^ (dl & 3)) << 4)];
        d0[0] = pb0; d0[1] = pb1;
        s16x8* d1 = (s16x8*)&b_lds[nxt][dl * PST + (((g0 + 1) ^ (dl & 3)) << 4)];
        d1[0] = pb2; d1[1] = pb3;
      }
    }
    __syncthreads();
  }
#pragma unroll
  for (int ni = 0; ni < 2; ++ni) {
    int nl = nh2 * 32 + ni * 16 + col;
    int dgl = nt * 64 + nl;
    float bb = bo[dgl];
#pragma unroll
    for (int u = 0; u < 4; ++u) {
      int s = mt * 32 + mi2 * 16 + quad * 4 + u;
      out[(size_t)s * DM + dgl] = acc[ni][u] + bb;
    }
  }
}

extern "C" void kernel_launch(void* const* d_in, const int* in_sizes, int n_in,
                              void* d_out, int out_size, void* d_ws, size_t ws_size,
                              hipStream_t stream) {
  const float* x    = (const float*)d_in[0];
  const float* w_qk = (const float*)d_in[1];
  const float* b_qk = (const float*)d_in[2];
  const float* w_v  = (const float*)d_in[3];
  const float* b_v  = (const float*)d_in[4];
  const float* w_o  = (const float*)d_in[5];
  const float* b_o  = (const float*)d_in[6];
  const float* rot  = (const float*)d_in[7];
  float* out = (float*)d_out;

  char* ws = (char*)d_ws;
  const size_t MB = 1024u * 1024u;
  short* qkb    = (short*)(ws);                       // 1 MB bf16
  short* vb     = (short*)(ws + 1 * MB);              // 1 MB bf16
  float* qkpart = (float*)(ws + 2 * MB);              // 12 MB (6 fp32 slabs)
  short* accumB = (short*)(ws + 2 * MB);              // 8 MB bf16 (alias head)
  int* perm2    = (int*)(ws + 10 * MB);               // 4 MB (alias tail;
                                                      // qkpart dead pre-bucket)
  float* qkf    = (float*)(ws + 18 * MB);             // 2 MB fp32 (hash input)
  short* wtqk   = (short*)(ws + 20 * MB);             // 1.5 MB (3 levels)
  short* wtv    = (short*)(ws + 20 * MB + 1536u * 1024);  // 0.5 MB
  short* wto    = (short*)(ws + 22 * MB);             // 0.5 MB
  int* cursor   = (int*)(ws + 22 * MB + 512u * 1024); // 128 ints (+pad)

  wprep_kernel<<<192, 256, 0, stream>>>(w_qk, w_v, w_o, wtqk, wtv, wto, cursor);
  projmm_kernel<<<896, 256, 0, stream>>>(x, wtqk, wtv, b_qk, b_v, qkpart, vb);
  sumslab_kernel<<<512, 256, 0, stream>>>(qkpart, qkf, qkb);
  bucket_kernel<<<(NH * N) / 256, 256, 0, stream>>>(qkf, rot, cursor, perm2);
  attn_kernel<<<NH * NB * 64, 512, 0, stream>>>(qkb, vb, perm2, cursor, accumB);
  outproj_kernel<<<256, 256, 0, stream>>>(accumB, wto, b_o, out);
}

// Round 14
// 185.693 us; speedup vs baseline: 1.7016x; 1.7016x over previous
//
#include <hip/hip_runtime.h>
#include <math.h>

#define S 1024
#define DM 512
#define H 8
#define HD 64
#define NH 8          // n_hashes
#define NB 16         // n_buckets
#define N 8192        // B*H*S
#define SCALE 0.125f  // 1/sqrt(64)
#define EXP2C 0.18033688f  // SCALE * log2(e)

typedef __attribute__((ext_vector_type(4))) float f32x4;
typedef __attribute__((ext_vector_type(8))) short s16x8;
typedef __attribute__((ext_vector_type(4))) short s16x4;

__device__ __forceinline__ short f2bf(float f) {  // RTNE float->bf16
  union { float f; unsigned u; } a; a.f = f;
  unsigned r = a.u + 0x7fffu + ((a.u >> 16) & 1u);
  return (short)(r >> 16);
}
__device__ __forceinline__ float bf2f(short h) {
  union { unsigned u; float f; } a; a.u = ((unsigned)(unsigned short)h) << 16;
  return a.f;
}
__device__ __forceinline__ int f2bf2(float lo, float hi) {
  return (int)(unsigned short)f2bf(lo) | (((int)f2bf(hi)) << 16);
}
// level-l component of the 3-way bf16 split x = x0 + x1 + x2 (+eps)
__device__ __forceinline__ short lev_bf(float v, int lev) {
  short h0 = f2bf(v);
  if (lev == 0) return h0;
  float r1 = v - bf2f(h0);
  short h1 = f2bf(r1);
  if (lev == 1) return h1;
  return f2bf(r1 - bf2f(h1));
}

#if __has_builtin(__builtin_amdgcn_mfma_f32_16x16x16_bf16)
#define MFMA_PV(a, b, c) __builtin_amdgcn_mfma_f32_16x16x16_bf16(a, b, c, 0, 0, 0)
#else
#define MFMA_PV(a, b, c) __builtin_amdgcn_mfma_f32_16x16x16bf16_1k(a, b, c, 0, 0, 0)
#endif

// ---------------- K0: weight prep — Wt[lev][d][k] bf16 (transposed, split)
__global__ __launch_bounds__(256) void wprep_kernel(
    const float* __restrict__ wqk, const float* __restrict__ wv,
    const float* __restrict__ wo,
    short* __restrict__ wtqk, short* __restrict__ wtv, short* __restrict__ wto,
    int* __restrict__ cz) {
  int tid = threadIdx.x;
  if (blockIdx.x == 0) cz[tid] = 0;   // cursor[128] + pad
  int mat = blockIdx.x >> 6;          // 0 qk, 1 v, 2 o
  int tile = blockIdx.x & 63;
  int kt = tile >> 3, dt = tile & 7;
  const float* w = (mat == 0) ? wqk : ((mat == 1) ? wv : wo);

  __shared__ float wlds[64 * 68];
  int kr = tid >> 2, c4 = tid & 3;
  const float4* src = (const float4*)(w + (size_t)(kt * 64 + kr) * DM + dt * 64 + c4 * 16);
#pragma unroll
  for (int i = 0; i < 4; ++i) {
    float4 v = src[i];
    float* d = &wlds[kr * 68 + c4 * 16 + i * 4];
    d[0] = v.x; d[1] = v.y; d[2] = v.z; d[3] = v.w;
  }
  __syncthreads();
  int dr = tid >> 2, kc = tid & 3;
  s16x8 h0a, h0b, h1a, h1b, h2a, h2b;
#pragma unroll
  for (int i = 0; i < 8; ++i) {
    float v = wlds[(kc * 16 + i) * 68 + dr];
    short a = f2bf(v); float r1 = v - bf2f(a);
    short b = f2bf(r1); short c = f2bf(r1 - bf2f(b));
    h0a[i] = a; h1a[i] = b; h2a[i] = c;
  }
#pragma unroll
  for (int i = 0; i < 8; ++i) {
    float v = wlds[(kc * 16 + 8 + i) * 68 + dr];
    short a = f2bf(v); float r1 = v - bf2f(a);
    short b = f2bf(r1); short c = f2bf(r1 - bf2f(b));
    h0b[i] = a; h1b[i] = b; h2b[i] = c;
  }
  size_t dst = (size_t)(dt * 64 + dr) * DM + kt * 64 + kc * 16;
  if (mat == 0) {
    s16x8* p0 = (s16x8*)(wtqk + dst);
    s16x8* p1 = (s16x8*)(wtqk + (size_t)DM * DM + dst);
    s16x8* p2 = (s16x8*)(wtqk + (size_t)2 * DM * DM + dst);
    p0[0] = h0a; p0[1] = h0b; p1[0] = h1a; p1[1] = h1b; p2[0] = h2a; p2[1] = h2b;
  } else if (mat == 1) {
    s16x8* p = (s16x8*)(wtv + dst); p[0] = h0a; p[1] = h0b;
  } else {
    s16x8* p = (s16x8*)(wto + dst); p[0] = h0a; p[1] = h0b;
  }
}

// ---------------- K1: MFMA projection GEMM, split-K balanced (verbatim)
#define PST 72
__global__ __launch_bounds__(256) void projmm_kernel(
    const float* __restrict__ x, const short* __restrict__ wtqk,
    const short* __restrict__ wtv,
    const float* __restrict__ bqk, const float* __restrict__ bv,
    float* __restrict__ qkpart, short* __restrict__ vb) {
  int mt = blockIdx.x & 15;
  int rest = blockIdx.x >> 4;   // 0..55
  int sp = rest >> 3;           // 0..5 qk split, 6 = v
  int head = rest & 7;
  bool isv = (sp == 6);
  int xl = isv ? 0 : ((0x210100 >> (sp << 2)) & 0xF);  // {0,0,1,0,1,2}
  int wl = isv ? 0 : ((0x012010 >> (sp << 2)) & 0xF);  // {0,1,0,2,1,0}
  const short* wt = isv ? wtv : (wtqk + (size_t)wl * DM * DM);

  __shared__ short a_lds[2][64 * PST];
  __shared__ short b_lds[2][64 * PST];

  int tid = threadIdx.x;
  int wave = tid >> 6, lane = tid & 63;
  int col = lane & 15, quad = lane >> 4;
  int mh = wave & 1, nh2 = wave >> 1;

  f32x4 acc[2][2];
#pragma unroll
  for (int i = 0; i < 2; ++i)
#pragma unroll
    for (int j = 0; j < 2; ++j) acc[i][j] = (f32x4){0.f, 0.f, 0.f, 0.f};

  int sr = tid >> 2, c4 = tid & 3;
  int gran = sr * PST + ((c4 ^ (sr & 3)) << 4);

  {  // stage chunk 0 into buffer 0
    const float4* xp = (const float4*)(x + (size_t)(mt * 64 + sr) * DM + c4 * 16);
    float4 f0 = xp[0], f1 = xp[1], f2 = xp[2], f3 = xp[3];
    float vv[16] = {f0.x,f0.y,f0.z,f0.w, f1.x,f1.y,f1.z,f1.w,
                    f2.x,f2.y,f2.z,f2.w, f3.x,f3.y,f3.z,f3.w};
    s16x8 ha, hb;
#pragma unroll
    for (int i = 0; i < 8; ++i) { ha[i] = lev_bf(vv[i], xl); hb[i] = lev_bf(vv[8 + i], xl); }
    s16x8* ad = (s16x8*)&a_lds[0][gran];
    ad[0] = ha; ad[1] = hb;
    const s16x8* wp = (const s16x8*)(wt + (size_t)(head * 64 + sr) * DM + c4 * 16);
    s16x8* bd = (s16x8*)&b_lds[0][gran];
    bd[0] = wp[0]; bd[1] = wp[1];
  }
  __syncthreads();

  for (int ci = 0; ci < 8; ++ci) {
    int cur = ci & 1, nxt = cur ^ 1;
    float4 pf0, pf1, pf2, pf3; s16x8 pw0, pw1;
    bool has = (ci + 1) < 8;
    if (has) {
      int kc = ci + 1;
      const float4* xp = (const float4*)(x + (size_t)(mt * 64 + sr) * DM + kc * 64 + c4 * 16);
      pf0 = xp[0]; pf1 = xp[1]; pf2 = xp[2]; pf3 = xp[3];
      const s16x8* wp = (const s16x8*)(wt + (size_t)(head * 64 + sr) * DM + kc * 64 + c4 * 16);
      pw0 = wp[0]; pw1 = wp[1];
    }
#pragma unroll
    for (int s2 = 0; s2 < 2; ++s2) {
      s16x8 af[2], bfv[2];
#pragma unroll
      for (int mi = 0; mi < 2; ++mi) {
        int row = mh * 32 + mi * 16 + col;
        int cidx = ((s2 << 1) + (quad >> 1)) ^ (row & 3);
        af[mi] = *(const s16x8*)&a_lds[cur][row * PST + (cidx << 4) + ((quad & 1) << 3)];
      }
#pragma unroll
      for (int ni = 0; ni < 2; ++ni) {
        int row = nh2 * 32 + ni * 16 + col;
        int cidx = ((s2 << 1) + (quad >> 1)) ^ (row & 3);
        bfv[ni] = *(const s16x8*)&b_lds[cur][row * PST + (cidx << 4) + ((quad & 1) << 3)];
      }
#pragma unroll
      for (int mi = 0; mi < 2; ++mi)
#pragma unroll
        for (int ni = 0; ni < 2; ++ni)
          acc[mi][ni] = __builtin_amdgcn_mfma_f32_16x16x32_bf16(af[mi], bfv[ni],
                                                               acc[mi][ni], 0, 0, 0);
    }
    if (has) {
      float vv[16] = {pf0.x,pf0.y,pf0.z,pf0.w, pf1.x,pf1.y,pf1.z,pf1.w,
                      pf2.x,pf2.y,pf2.z,pf2.w, pf3.x,pf3.y,pf3.z,pf3.w};
      s16x8 ha, hb;
#pragma unroll
      for (int i = 0; i < 8; ++i) { ha[i] = lev_bf(vv[i], xl); hb[i] = lev_bf(vv[8 + i], xl); }
      s16x8* ad = (s16x8*)&a_lds[nxt][gran];
      ad[0] = ha; ad[1] = hb;
      s16x8* bd = (s16x8*)&b_lds[nxt][gran];
      bd[0] = pw0; bd[1] = pw1;
    }
    __syncthreads();
  }
  if (isv) {
#pragma unroll
    for (int ni = 0; ni < 2; ++ni) {
      int nl = nh2 * 32 + ni * 16 + col;
      float bb = bv[head * 64 + nl];
#pragma unroll
      for (int mi = 0; mi < 2; ++mi)
#pragma unroll
        for (int u = 0; u < 4; ++u) {
          int s = mt * 64 + mh * 32 + mi * 16 + quad * 4 + u;
          vb[((size_t)head * S + s) * HD + nl] = f2bf(acc[mi][ni][u] + bb);
        }
    }
  } else {
    float* dst = qkpart + (size_t)sp * N * HD;
#pragma unroll
    for (int ni = 0; ni < 2; ++ni) {
      int nl = nh2 * 32 + ni * 16 + col;
      float bb = (sp == 0) ? bqk[head * 64 + nl] : 0.f;
#pragma unroll
      for (int mi = 0; mi < 2; ++mi)
#pragma unroll
        for (int u = 0; u < 4; ++u) {
          int s = mt * 64 + mh * 32 + mi * 16 + quad * 4 + u;
          dst[((size_t)head * S + s) * HD + nl] = acc[mi][ni][u] + bb;
        }
    }
  }
}

// ---------------- K2a: collapse the 6 fp32 slabs once -> qkf fp32 + qkb bf16
__global__ __launch_bounds__(256) void sumslab_kernel(
    const float* __restrict__ qkpart, float* __restrict__ qkf,
    short* __restrict__ qkb) {
  int idx = blockIdx.x * 256 + threadIdx.x;  // 0 .. N*HD/4 - 1
  f32x4 s = ((const f32x4*)qkpart)[idx];
#pragma unroll
  for (int sl = 1; sl < 6; ++sl)
    s += ((const f32x4*)(qkpart + (size_t)sl * N * HD))[idx];
  ((f32x4*)qkf)[idx] = s;
  int2 pk = make_int2(f2bf2(s[0], s[1]), f2bf2(s[2], s[3]));
  *(int2*)(qkb + (size_t)idx * 4) = pk;
}

// ---------------- K2b: LSH buckets + DIRECT per-bucket list build (verbatim)
__global__ __launch_bounds__(256) void bucket_kernel(
    const float* __restrict__ qkf, const float* __restrict__ rot,
    int* __restrict__ cursor, int* __restrict__ perm2) {
  __shared__ float Rl[HD * 8];   // 2 KB
  int tid = threadIdx.x;
  int g = blockIdx.x * 256 + tid;
  int n = g & (N - 1);
  int r = g >> 13;
  int h = n >> 10;
  int lane = tid & 63;
  const float* R = rot + (size_t)((r * H + h) * HD) * 8;
  if (tid < 128) ((f32x4*)Rl)[tid] = ((const f32x4*)R)[tid];

  f32x4 qv[16];
  const f32x4* q4 = (const f32x4*)(qkf + (size_t)n * HD);
#pragma unroll
  for (int d4 = 0; d4 < 16; ++d4) qv[d4] = q4[d4];
  __syncthreads();

  float v[8];
#pragma unroll
  for (int c = 0; c < 8; ++c) v[c] = 0.f;
#pragma unroll
  for (int d4 = 0; d4 < 16; ++d4) {
    f32x4 q = qv[d4];
#pragma unroll
    for (int j = 0; j < 4; ++j) {
      const f32x4* Rr = (const f32x4*)&Rl[(d4 * 4 + j) * 8];
      f32x4 r0 = Rr[0], r1 = Rr[1];
      float qj = q[j];
#pragma unroll
      for (int c = 0; c < 4; ++c) v[c] = fmaf(qj, r0[c], v[c]);
#pragma unroll
      for (int c = 0; c < 4; ++c) v[4 + c] = fmaf(qj, r1[c], v[4 + c]);
    }
  }
  float best = v[0];
  int bi = 0;
#pragma unroll
  for (int c = 1; c < 16; ++c) {
    float val = (c < 8) ? v[c] : -v[c - 8];
    if (val > best) { best = val; bi = c; }
  }
  for (int bk = 0; bk < NB; ++bk) {
    unsigned long long mask = __ballot(bi == bk);
    if (!mask) continue;
    int leader = __ffsll((long long)mask) - 1;
    int base = 0;
    if (lane == leader) base = atomicAdd(&cursor[(r << 4) + bk], __popcll(mask));
    base = __shfl(base, leader);
    if (bi == bk) {
      int rank = __popcll(mask & ((1ull << lane) - 1ull));
      perm2[(((size_t)(r << 4) + bk) << 13) + base + rank] = n;
    }
  }
}

// ---------------- K3: MFMA attention over per-bucket lists. Grid indexing:
// chunk in HIGH bits (bx = chunk*128 + rb) so working blocks (chunk<~5) form
// a contiguous prefix spread across all CUs — r13's low-bit chunk encoding
// aliased with the 256-CU round-robin (256 ≡ 0 mod 64) and serialized all
// work onto 16 CUs (occupancy 6.6%, 3.5x dur).
#define KT 64
#define KST 72
#define VST 72
__global__ __launch_bounds__(512) void attn_kernel(
    const short* __restrict__ qkb, const short* __restrict__ vb,
    const int* __restrict__ perm2, const int* __restrict__ cursor,
    short* __restrict__ accumB) {
  int bx = blockIdx.x;
  int rb = bx & 127;            // r*16 + b
  int chunk = bx >> 7;          // 0..63, high bits
  int r = rb >> 4;
  int b = rb & 15;
  int cnt = cursor[rb];
  int q0 = chunk << 7;
  if (q0 >= cnt) return;
  const int* plist = perm2 + ((size_t)rb << 13);

  int tid = threadIdx.x;
  int wave = tid >> 6, lane = tid & 63;
  int col = lane & 15, quad = lane >> 4;

  __shared__ short k_lds[2][KT * KST];
  __shared__ short v_lds[2][KT * VST];

  int qslot = q0 + (wave << 4) + col;
  bool qvalid = qslot < cnt;
  int qidx = plist[qvalid ? qslot : 0];

  for (int e = tid; e < KT * VST; e += 512) ((int*)v_lds)[e] = 0;

  s16x8 qa[2];
#pragma unroll
  for (int s2 = 0; s2 < 2; ++s2)
    qa[s2] = *(const s16x8*)(qkb + (size_t)qidx * HD + s2 * 32 + quad * 8);
  __syncthreads();   // zero-init fully retired before staging writes

  float lsum = 0.f;
  f32x4 o0 = {0,0,0,0}, o1 = {0,0,0,0}, o2 = {0,0,0,0}, o3 = {0,0,0,0};

  int jsk = tid >> 2, csk = tid & 3;
  bool stager = tid < 256;
  int kgran = jsk * KST + ((csk ^ (jsk & 3)) << 4);
  int vgran = jsk * VST + (csk << 4);

  {  // stage tile 0 into buffer 0
    int nj = min(KT, cnt);
    if (stager && jsk < nj) {
      int gk = plist[jsk];
      const s16x8* kp = (const s16x8*)(qkb + (size_t)gk * HD + (csk << 4));
      const s16x8* vp = (const s16x8*)(vb + (size_t)gk * HD + (csk << 4));
      s16x8 a0 = kp[0], a1 = kp[1], b0 = vp[0], b1 = vp[1];
      s16x8* kd = (s16x8*)&k_lds[0][kgran];
      kd[0] = a0; kd[1] = a1;
      s16x8* vd = (s16x8*)&v_lds[0][vgran];
      vd[0] = b0; vd[1] = b1;
    }
  }
  __syncthreads();

  int ntiles = (cnt + KT - 1) >> 6;
  for (int t = 0; t < ntiles; ++t) {
    int jt = t << 6;
    int cur = t & 1, nxt = cur ^ 1;
    s16x8 a0, a1, b0, b1;
    bool pf_ok = false;
    int jn = jt + KT;
    if (jn < cnt && stager) {
      int njn = min(KT, cnt - jn);
      if (jsk < njn) {
        pf_ok = true;
        int gk = plist[jn + jsk];
        const s16x8* kp = (const s16x8*)(qkb + (size_t)gk * HD + (csk << 4));
        const s16x8* vp = (const s16x8*)(vb + (size_t)gk * HD + (csk << 4));
        a0 = kp[0]; a1 = kp[1]; b0 = vp[0]; b1 = vp[1];
      }
    }
    int c_hi = min(4, (cnt - jt + 15) >> 4);
    for (int c16 = 0; c16 < c_hi; ++c16) {
      f32x4 sacc = {0,0,0,0};
      int key = (c16 << 4) + col;
      const short* kb = &k_lds[cur][key * KST];
#pragma unroll
      for (int s2 = 0; s2 < 2; ++s2) {
        int cidx = ((s2 << 1) + (quad >> 1)) ^ (key & 3);
        s16x8 kf = *(const s16x8*)&kb[(cidx << 4) + ((quad & 1) << 3)];
        sacc = __builtin_amdgcn_mfma_f32_16x16x32_bf16(kf, qa[s2], sacc, 0, 0, 0);
      }
      int kbase = jt + (c16 << 4) + (quad << 2);
      float pw[4];
      if (kbase + 4 <= cnt) {           // full chunk: no masking
#pragma unroll
        for (int u = 0; u < 4; ++u) pw[u] = exp2f(sacc[u] * EXP2C);
      } else {
#pragma unroll
        for (int u = 0; u < 4; ++u)
          pw[u] = (kbase + u < cnt) ? exp2f(sacc[u] * EXP2C) : 0.f;
      }
      lsum += (pw[0] + pw[1]) + (pw[2] + pw[3]);
      s16x4 pfr;
      pfr[0] = f2bf(pw[0]); pfr[1] = f2bf(pw[1]);
      pfr[2] = f2bf(pw[2]); pfr[3] = f2bf(pw[3]);
      const short* vbp = &v_lds[cur][((c16 << 4) + (quad << 2)) * VST + col];
#pragma unroll
      for (int c = 0; c < 4; ++c) {
        s16x4 vfr;
#pragma unroll
        for (int j = 0; j < 4; ++j)
          vfr[j] = vbp[j * VST + (c << 4)];
        if (c == 0) o0 = MFMA_PV(pfr, vfr, o0);
        else if (c == 1) o1 = MFMA_PV(pfr, vfr, o1);
        else if (c == 2) o2 = MFMA_PV(pfr, vfr, o2);
        else o3 = MFMA_PV(pfr, vfr, o3);
      }
    }
    if (pf_ok) {
      s16x8* kd = (s16x8*)&k_lds[nxt][kgran];
      kd[0] = a0; kd[1] = a1;
      s16x8* vd = (s16x8*)&v_lds[nxt][vgran];
      vd[0] = b0; vd[1] = b1;
    }
    __syncthreads();
  }

  lsum += __shfl_xor(lsum, 16);
  lsum += __shfl_xor(lsum, 32);
  float inv = 1.f / lsum;
#pragma unroll
  for (int u = 0; u < 4; ++u) {
    int slot = (quad << 2) + u;
    int spos = q0 + (wave << 4) + slot;
    float inv_u = __shfl(inv, slot);
    int qidx_u = __shfl(qidx, slot);
    if (spos < cnt) {
      short* dst = accumB + ((size_t)r * N + qidx_u) * HD + col;
      dst[0]  = f2bf(o0[u] * inv_u);
      dst[16] = f2bf(o1[u] * inv_u);
      dst[32] = f2bf(o2[u] * inv_u);
      dst[48] = f2bf(o3[u] * inv_u);
    }
  }
}

// ---------------- K4: MFMA output projection; A from bf16 accumB (verbatim)
__global__ __launch_bounds__(256) void outproj_kernel(
    const short* __restrict__ accumB, const short* __restrict__ wto,
    const float* __restrict__ bo, float* __restrict__ out) {
  int mt = blockIdx.x & 31;   // s-tile of 32
  int nt = blockIdx.x >> 5;   // d-tile of 64
  __shared__ short a_lds[2][32 * PST];
  __shared__ short b_lds[2][64 * PST];
  int tid = threadIdx.x;
  int wave = tid >> 6, lane = tid & 63;
  int col = lane & 15, quad = lane >> 4;
  int mi2 = wave & 1, nh2 = wave >> 1;

  f32x4 acc[2];
  acc[0] = (f32x4){0.f,0.f,0.f,0.f};
  acc[1] = (f32x4){0.f,0.f,0.f,0.f};

  bool isA = tid < 128;
  int sr = tid >> 2, c4 = tid & 3;
  int agran = sr * PST + ((c4 ^ (sr & 3)) << 4);
  int dl = (tid - 128) >> 1, gp = tid & 1;

  {  // stage chunk 0
    if (isA) {
      size_t abase = ((size_t)0 * S + mt * 32 + sr) * HD + c4 * 16;
      float a16[16];
#pragma unroll
      for (int i = 0; i < 16; ++i) a16[i] = 0.f;
#pragma unroll
      for (int r = 0; r < NH; ++r) {
        const short* ap = accumB + (size_t)r * N * HD + abase;
        s16x8 h0 = *(const s16x8*)ap, h1 = *(const s16x8*)(ap + 8);
#pragma unroll
        for (int i = 0; i < 8; ++i) { a16[i] += bf2f(h0[i]); a16[8 + i] += bf2f(h1[i]); }
      }
      s16x8 ha, hb;
#pragma unroll
      for (int i = 0; i < 8; ++i) {
        ha[i] = f2bf(a16[i] * 0.125f); hb[i] = f2bf(a16[8 + i] * 0.125f);
      }
      s16x8* ad = (s16x8*)&a_lds[0][agran];
      ad[0] = ha; ad[1] = hb;
    } else {
      const s16x8* wp = (const s16x8*)(wto + (size_t)(nt * 64 + dl) * DM + gp * 32);
      int g0 = gp * 2;
      s16x8* d0 = (s16x8*)&b_lds[0][dl * PST + ((g0 ^ (dl & 3)) << 4)];
      d0[0] = wp[0]; d0[1] = wp[1];
      s16x8* d1 = (s16x8*)&b_lds[0][dl * PST + (((g0 + 1) ^ (dl & 3)) << 4)];
      d1[0] = wp[2]; d1[1] = wp[3];
    }
  }
  __syncthreads();

  for (int kc = 0; kc < 8; ++kc) {
    int cur = kc & 1, nxt = cur ^ 1;
    bool has = kc + 1 < 8;
    float a16[16];
    s16x8 pb0, pb1, pb2, pb3;
    if (has) {
      if (isA) {
        size_t abase = ((size_t)(kc + 1) * S + mt * 32 + sr) * HD + c4 * 16;
#pragma unroll
        for (int i = 0; i < 16; ++i) a16[i] = 0.f;
#pragma unroll
        for (int r = 0; r < NH; ++r) {
          const short* ap = accumB + (size_t)r * N * HD + abase;
          s16x8 h0 = *(const s16x8*)ap, h1 = *(const s16x8*)(ap + 8);
#pragma unroll
          for (int i = 0; i < 8; ++i) { a16[i] += bf2f(h0[i]); a16[8 + i] += bf2f(h1[i]); }
        }
      } else {
        const s16x8* wp = (const s16x8*)(wto + (size_t)(nt * 64 + dl) * DM +
                                         (kc + 1) * 64 + gp * 32);
        pb0 = wp[0]; pb1 = wp[1]; pb2 = wp[2]; pb3 = wp[3];
      }
    }
#pragma unroll
    for (int s2 = 0; s2 < 2; ++s2) {
      int arow = mi2 * 16 + col;
      int acidx = ((s2 << 1) + (quad >> 1)) ^ (arow & 3);
      s16x8 af = *(const s16x8*)&a_lds[cur][arow * PST + (acidx << 4) + ((quad & 1) << 3)];
      s16x8 bfv[2];
#pragma unroll
      for (int ni = 0; ni < 2; ++ni) {
        int brow = nh2 * 32 + ni * 16 + col;
        int bcidx = ((s2 << 1) + (quad >> 1)) ^ (brow & 3);
        bfv[ni] = *(const s16x8*)&b_lds[cur][brow * PST + (bcidx << 4) + ((quad & 1) << 3)];
      }
#pragma unroll
      for (int ni = 0; ni < 2; ++ni)
        acc[ni] = __builtin_amdgcn_mfma_f32_16x16x32_bf16(af, bfv[ni], acc[ni], 0, 0, 0);
    }
    if (has) {
      if (isA) {
        s16x8 ha, hb;
#pragma unroll
        for (int i = 0; i < 8; ++i) {
          ha[i] = f2bf(a16[i] * 0.125f); hb[i] = f2bf(a16[8 + i] * 0.125f);
        }
        s16x8* ad = (s16x8*)&a_lds[nxt][agran];
        ad[0] = ha; ad[1] = hb;
      } else {
        int g0 = gp * 2;
        s16x8* d0 = (s16x8*)&b_lds[nxt][dl * PST + ((g0 ^ (dl & 3)) << 4)];
        d0[0] = pb0; d0[1] = pb1;
        s16x8* d1 = (s16x8*)&b_lds[nxt][dl * PST + (((g0 + 1) ^ (dl & 3)) << 4)];
        d1[0] = pb2; d1[1] = pb3;
      }
    }
    __syncthreads();
  }
#pragma unroll
  for (int ni = 0; ni < 2; ++ni) {
    int nl = nh2 * 32 + ni * 16 + col;
    int dgl = nt * 64 + nl;
    float bb = bo[dgl];
#pragma unroll
    for (int u = 0; u < 4; ++u) {
      int s = mt * 32 + mi2 * 16 + quad * 4 + u;
      out[(size_t)s * DM + dgl] = acc[ni][u] + bb;
    }
  }
}

extern "C" void kernel_launch(void* const* d_in, const int* in_sizes, int n_in,
                              void* d_out, int out_size, void* d_ws, size_t ws_size,
                              hipStream_t stream) {
  const float* x    = (const float*)d_in[0];
  const float* w_qk = (const float*)d_in[1];
  const float* b_qk = (const float*)d_in[2];
  const float* w_v  = (const float*)d_in[3];
  const float* b_v  = (const float*)d_in[4];
  const float* w_o  = (const float*)d_in[5];
  const float* b_o  = (const float*)d_in[6];
  const float* rot  = (const float*)d_in[7];
  float* out = (float*)d_out;

  char* ws = (char*)d_ws;
  const size_t MB = 1024u * 1024u;
  short* qkb    = (short*)(ws);                       // 1 MB bf16
  short* vb     = (short*)(ws + 1 * MB);              // 1 MB bf16
  float* qkpart = (float*)(ws + 2 * MB);              // 12 MB (6 fp32 slabs)
  short* accumB = (short*)(ws + 2 * MB);              // 8 MB bf16 (alias head)
  int* perm2    = (int*)(ws + 10 * MB);               // 4 MB (alias tail;
                                                      // qkpart dead pre-bucket)
  float* qkf    = (float*)(ws + 18 * MB);             // 2 MB fp32 (hash input)
  short* wtqk   = (short*)(ws + 20 * MB);             // 1.5 MB (3 levels)
  short* wtv    = (short*)(ws + 20 * MB + 1536u * 1024);  // 0.5 MB
  short* wto    = (short*)(ws + 22 * MB);             // 0.5 MB
  int* cursor   = (int*)(ws + 22 * MB + 512u * 1024); // 128 ints (+pad)

  wprep_kernel<<<192, 256, 0, stream>>>(w_qk, w_v, w_o, wtqk, wtv, wto, cursor);
  projmm_kernel<<<896, 256, 0, stream>>>(x, wtqk, wtv, b_qk, b_v, qkpart, vb);
  sumslab_kernel<<<512, 256, 0, stream>>>(qkpart, qkf, qkb);
  bucket_kernel<<<(NH * N) / 256, 256, 0, stream>>>(qkf, rot, cursor, perm2);
  attn_kernel<<<64 * 128, 512, 0, stream>>>(qkb, vb, perm2, cursor, accumB);
  outproj_kernel<<<256, 256, 0, stream>>>(accumB, wto, b_o, out);
}